// Round 5
// baseline (511.330 us; speedup 1.0000x reference)
//
// GCNTox21 fused pipeline — MI355X/gfx950.  R17 == R16 resubmit (infra
// failure last round: "container failed twice", no compile/accuracy verdict).
// Model (R13-R15 evidence): k_msg4 is pinned at ~130MB / ~2TB/s on the
// L2-miss path; concurrency/staging are irrelevant, only BYTES + pattern
// move it.  R16/R17 cuts bytes:
//  (a) Q stored as fp8 e4m3 for layers 0/1 (HW cvt_pk encode in pq
//      epilogue, cvt_pk decode in msg4 => ~1 VALU inst/edge).  Q-gather
//      traffic 75 -> 38MB/dispatch.  Layer-2 Q stays bf16 (error budget).
//  (b) eh as packed bf16 (ehb, 32B/edge): 12.8 -> 6.4MB x3 dispatches.
//  (c) srcs[] int-only (msg4 no longer needs cpair.y): 1.6 -> 0.8MB.
//  (d) R14 prefetch dropped (proven neutral).
// Fallback plan: if absmax blows the threshold, revert (a) only.
// GEMM XCD-affine remap + CSR-order eh stream kept from R15.
#include <hip/hip_runtime.h>
#include <hip/hip_bf16.h>

typedef unsigned int  uint;
typedef unsigned short ushort;
typedef unsigned char uchar;
typedef float  f32x2  __attribute__((ext_vector_type(2)));
typedef float  f32x4  __attribute__((ext_vector_type(4)));
typedef __bf16 bf16x8 __attribute__((ext_vector_type(8)));

#define DEV static __device__ __forceinline__

DEV float  b2f(ushort b){ return __uint_as_float(((uint)b) << 16); }
DEV float  lo2f(uint u){ return __uint_as_float(u << 16); }
DEV float  hi2f(uint u){ return __uint_as_float(u & 0xffff0000u); }
DEV ushort f2b(float f){           // RNE float->bf16
  uint u = __float_as_uint(f);
  u += 0x7fffu + ((u >> 16) & 1u);
  return (ushort)(u >> 16);
}
DEV uint pk2(float a, float b){ return (uint)f2b(a) | ((uint)f2b(b) << 16); }
DEV void unpack8(uint4 v, float* f){
  f[0]=lo2f(v.x); f[1]=hi2f(v.x); f[2]=lo2f(v.y); f[3]=hi2f(v.y);
  f[4]=lo2f(v.z); f[5]=hi2f(v.z); f[6]=lo2f(v.w); f[7]=hi2f(v.w);
}
DEV int ld_idx(const void* p, int flag, long long i){
  return flag ? ((const int*)p)[i] : (int)((const long long*)p)[i];
}
DEV float ldf(const void* p, int f, int i){
  return f ? ((const float*)p)[i] : b2f(((const ushort*)p)[i]);
}
DEV int clampi(int v, int lo, int hi){ return v < lo ? lo : (v > hi ? hi : v); }

// async 16B global -> LDS (DMA).  LDS dest = wave-uniform base + lane*16.
DEV void ld16(const ushort* g, ushort* l){
  __builtin_amdgcn_global_load_lds(
      (const __attribute__((address_space(1))) void*)g,
      (__attribute__((address_space(3))) void*)l, 16, 0, 0);
}

// ---------- zero (deg+fill) + probes in one launch ----------
__global__ __launch_bounds__(256) void k_zero_probe(const uint* __restrict__ ei,
    const uint* __restrict__ xw, int* __restrict__ iflag, int* __restrict__ fflag,
    int* __restrict__ zbase, int zn){
  int i = blockIdx.x*256 + threadIdx.x;
  if (i < zn) zbase[i] = 0;
  if (blockIdx.x == 0){
    __shared__ int anyI, cntF;
    if (threadIdx.x == 0){ anyI = 0; cntF = 0; }
    __syncthreads();
    int li = 0, lc = 0;
    for (int k = threadIdx.x; k < 1024; k += 256){
      if (ei[2*k + 1] != 0u) li = 1;            // int64 => odd words all 0
      float f = fabsf(__uint_as_float(xw[k]));  // fp32 N(0,1) words decode sane
      if (f > 1e-6f && f < 1e6f) lc++;
    }
    if (li) atomicOr(&anyI, 1);
    atomicAdd(&cntF, lc);
    __syncthreads();
    if (threadIdx.x == 0){ *iflag = anyI; *fflag = (2*cntF > 1024) ? 1 : 0; }
  }
}

// ---------- CSR count + scan ----------
__global__ __launch_bounds__(256) void k_count(const void* __restrict__ ei,
    const int* __restrict__ flag, int* __restrict__ cnt, int E, int N){
  int e = blockIdx.x*256 + threadIdx.x;
  if (e >= E) return;
  int d = clampi(ld_idx(ei, *flag, (long long)E + e), 0, N-1);
  atomicAdd(&cnt[d], 1);
}

__global__ __launch_bounds__(1024) void k_scan(const int* __restrict__ deg, int* __restrict__ rp, int n){
  __shared__ int part[1024];
  int t = threadIdx.x;
  int chunk = (n + 1023) >> 10;
  int base = t * chunk;
  int s = 0;
  for (int i = 0; i < chunk; i++){ int j = base + i; if (j < n) s += deg[j]; }
  part[t] = s;
  __syncthreads();
  for (int off = 1; off < 1024; off <<= 1){
    int v = (t >= off) ? part[t - off] : 0;
    __syncthreads();
    part[t] += v;
    __syncthreads();
  }
  int run = part[t] - s;
  for (int i = 0; i < chunk; i++){ int j = base + i; if (j < n){ rp[j] = run; run += deg[j]; } }
  if (t == 1023) rp[n] = part[1023];
}

// ---------- mega: CSR-fill + weight-cvt + edge-enc + node-enc ----------
struct CvtTab { const void* src[6]; ushort* dst[6]; int n[6]; int bstart[6]; int nseg; };

__global__ __launch_bounds__(256) void k_mega(
    const void* __restrict__ ei, const int* __restrict__ iflag,
    const int* __restrict__ rp, int* __restrict__ fill, int2* __restrict__ cpair,
    CvtTab ct, const int* __restrict__ fflag,
    const void* __restrict__ ea, const void* __restrict__ eew, const void* __restrict__ eeb,
    const void* __restrict__ x, const void* __restrict__ nw, const void* __restrict__ nbias,
    float* __restrict__ eh, ushort* __restrict__ h,
    int E, int N, int FB, int CB, int EB){
  int b = blockIdx.x;
  int t = threadIdx.x;
  if (b < FB){
    // ---- CSR fill ----
    int e = b*256 + t;
    if (e >= E) return;
    int f = *iflag;
    int s = clampi(ld_idx(ei, f, e), 0, N-1);
    int d = clampi(ld_idx(ei, f, (long long)E + e), 0, N-1);
    int pos = clampi(rp[d] + atomicAdd(&fill[d], 1), 0, E-1);
    cpair[pos] = make_int2(s, e);
  } else if (b < FB + CB){
    // ---- weight conversion (w1 x3, w2 x3) ----
    int cb = b - FB;
    int s = ct.nseg - 1;
    for (int i = 1; i < ct.nseg; i++) if (cb < ct.bstart[i]){ s = i - 1; break; }
    int rel = cb - ct.bstart[s];
    const void* sp = ct.src[s];
    ushort* d = ct.dst[s];
    int f = *fflag;
    int end = ct.n[s]; int cap = rel*8192 + 8192; if (cap < end) end = cap;
    for (int i = rel*8192 + t; i < end; i += 256)
      d[i] = f ? f2b(((const float*)sp)[i]) : ((const ushort*)sp)[i];
  } else if (b < FB + CB + EB){
    // ---- edge encoder: eh = relu(ea @ eew.T + eeb), pre-unpacked f32 ----
    __shared__ float ws[128];
    __shared__ float bs[16];
    int f = *fflag;
    if (t < 128) ws[t] = ldf(eew, f, t);
    if (t < 16)  bs[t] = ldf(eeb, f, t);
    __syncthreads();
    int e = (b - FB - CB)*256 + t;
    if (e >= E) return;
    float a[8];
    if (f){
      const float4* ap = (const float4*)((const float*)ea + (size_t)e*8);
      float4 v0 = ap[0], v1 = ap[1];
      a[0]=v0.x; a[1]=v0.y; a[2]=v0.z; a[3]=v0.w;
      a[4]=v1.x; a[5]=v1.y; a[6]=v1.z; a[7]=v1.w;
    } else {
      uint4 av = *(const uint4*)((const ushort*)ea + (size_t)e*8);
      unpack8(av, a);
    }
    float o[16];
    #pragma unroll
    for (int c = 0; c < 16; c++){
      float s = bs[c];
      #pragma unroll
      for (int j = 0; j < 8; j++) s += a[j]*ws[c*8+j];
      o[c] = fmaxf(s, 0.f);
    }
    f32x4* op = (f32x4*)(eh + (size_t)e*16);
    #pragma unroll
    for (int q4 = 0; q4 < 4; q4++){
      f32x4 v = {o[q4*4+0], o[q4*4+1], o[q4*4+2], o[q4*4+3]};
      op[q4] = v;
    }
  } else {
    // ---- node encoder: h = relu(x @ nw.T + nb), 4 nodes/block ----
    __shared__ float xs[4][32];
    int f = *fflag;
    int nb = (b - FB - CB - EB)*4;
    if (t < 128){
      int ni = t >> 5, ci = t & 31;
      int n = nb + ni; if (n >= N) n = N - 1;
      xs[ni][ci] = f ? ((const float*)x)[(size_t)n*32 + ci]
                     : b2f(((const ushort*)x)[(size_t)n*32 + ci]);
    }
    __syncthreads();
    float wr[32];
    if (f){
      const float4* wp = (const float4*)((const float*)nw + (size_t)t*32);
      #pragma unroll
      for (int q4 = 0; q4 < 8; q4++){
        float4 v = wp[q4];
        wr[q4*4+0]=v.x; wr[q4*4+1]=v.y; wr[q4*4+2]=v.z; wr[q4*4+3]=v.w;
      }
    } else {
      const uint4* wp = (const uint4*)((const ushort*)nw + (size_t)t*32);
      unpack8(wp[0], wr); unpack8(wp[1], wr+8); unpack8(wp[2], wr+16); unpack8(wp[3], wr+24);
    }
    float bv = ldf(nbias, f, t);
    #pragma unroll
    for (int ni = 0; ni < 4; ni++){
      int n = nb + ni;
      if (n >= N) break;
      float s = bv;
      #pragma unroll
      for (int k = 0; k < 32; k++) s += xs[ni][k]*wr[k];
      h[(size_t)n*256 + t] = f2b(fmaxf(s, 0.f));
    }
  }
}

// ---------- reorder: ehb[pos] = bf16(eh[cpair[pos].y]); srcs[pos]=cpair[pos].x --
__global__ __launch_bounds__(256) void k_reorder(const int2* __restrict__ cpair,
    const float* __restrict__ eh, uint* __restrict__ ehb, int* __restrict__ srcs, int E){
  int pos = blockIdx.x*256 + threadIdx.x;
  if (pos >= E) return;
  int2 cp = cpair[pos];
  srcs[pos] = cp.x;
  const f32x4* ep = (const f32x4*)(eh + (size_t)cp.y*16);
  f32x4 a = ep[0], b = ep[1], c = ep[2], d = ep[3];
  uint4 o0 = { pk2(a.x,a.y), pk2(a.z,a.w), pk2(b.x,b.y), pk2(b.z,b.w) };
  uint4 o1 = { pk2(c.x,c.y), pk2(c.z,c.w), pk2(d.x,d.y), pk2(d.z,d.w) };
  ((uint4*)ehb)[(size_t)pos*2]     = o0;
  ((uint4*)ehb)[(size_t)pos*2 + 1] = o1;
}

// ---------- LDS-staged 128x128 GEMM: P/Q producer (XCD-affine remap) ----------
// QF8: Q written as fp8 e4m3 bytes (HW cvt), P always bf16.
template<int QF8>
__global__ __launch_bounds__(256) void k_gemm_pq_lds(const ushort* __restrict__ A,
    const ushort* __restrict__ w1, int M, int Nc,
    ushort* __restrict__ P, void* __restrict__ Qout){
  const int MT = (M + 127) >> 7;
  const int YC = Nc >> 6;            // total y-variants: 8 (C=512) / 4 (C=256)
  int jb = blockIdx.x;
  int gx = jb & 7, rr = jb >> 3;
  int sx = rr / YC, yy = rr % YC;
  const int Tm = sx*8 + gx;
  if (Tm >= MT) return;
  __shared__ ushort As[128*32];
  __shared__ ushort Bs[128*32];
  const int t = threadIdx.x;
  const int lane = t & 63;
  const int wv = t >> 6;
  const int m0 = Tm*128;
  const int yc = Nc >> 7;
  const int isQ = yy >= yc;
  const int n0 = (isQ ? yy - yc : yy)*128;
  const ushort* W = w1 + (isQ ? 256 : 0);
  const int lr = lane & 15;
  const int qq = lane >> 4;
  int srow0 = t >> 2,         sq0 = t & 3;
  int srow1 = (256 + t) >> 2, sq1 = t & 3;
  int ga0 = m0 + srow0; if (ga0 >= M) ga0 = M - 1;
  int ga1 = m0 + srow1; if (ga1 >= M) ga1 = M - 1;
  f32x4 acc[2][8];
  #pragma unroll
  for (int f = 0; f < 2; f++)
    #pragma unroll
    for (int j = 0; j < 8; j++) acc[f][j] = {0.f,0.f,0.f,0.f};
  for (int k0 = 0; k0 < 256; k0 += 32){
    ld16(A + (size_t)ga0*256 + k0 + sq0*8, &As[(size_t)t*8]);
    ld16(A + (size_t)ga1*256 + k0 + sq1*8, &As[(size_t)(256+t)*8]);
    ld16(W + (size_t)(n0 + srow0)*528 + k0 + sq0*8, &Bs[(size_t)t*8]);
    ld16(W + (size_t)(n0 + srow1)*528 + k0 + sq1*8, &Bs[(size_t)(256+t)*8]);
    __syncthreads();
    bf16x8 a0 = *(const bf16x8*)&As[(wv*32 + lr)*32 + qq*8];
    bf16x8 a1 = *(const bf16x8*)&As[(wv*32 + 16 + lr)*32 + qq*8];
    #pragma unroll
    for (int j = 0; j < 8; j++){
      bf16x8 b = *(const bf16x8*)&Bs[(j*16 + lr)*32 + qq*8];
      acc[0][j] = __builtin_amdgcn_mfma_f32_16x16x32_bf16(a0, b, acc[0][j], 0, 0, 0);
      acc[1][j] = __builtin_amdgcn_mfma_f32_16x16x32_bf16(a1, b, acc[1][j], 0, 0, 0);
    }
    __syncthreads();
  }
  if (QF8 && isQ){
    uchar* Cq = (uchar*)Qout;
    #pragma unroll
    for (int f = 0; f < 2; f++){
      #pragma unroll
      for (int r = 0; r < 4; r++){
        int row = m0 + wv*32 + f*16 + qq*4 + r;
        if (row >= M) continue;
        #pragma unroll
        for (int j = 0; j < 8; j++){
          uint pk = (uint)__builtin_amdgcn_cvt_pk_fp8_f32(acc[f][j][r], 0.f, 0, false);
          Cq[(size_t)row*Nc + n0 + j*16 + lr] = (uchar)(pk & 0xffu);
        }
      }
    }
  } else {
    ushort* Cb = isQ ? (ushort*)Qout : P;
    #pragma unroll
    for (int f = 0; f < 2; f++){
      #pragma unroll
      for (int r = 0; r < 4; r++){
        int row = m0 + wv*32 + f*16 + qq*4 + r;
        if (row >= M) continue;
        #pragma unroll
        for (int j = 0; j < 8; j++)
          Cb[(size_t)row*Nc + n0 + j*16 + lr] = f2b(acc[f][j][r]);
      }
    }
  }
}

// ---------- LDS-staged 64x128 GEMM + bias + deg-mask + BN + relu ----------
// XCD-affine remap kept.  Small params read raw (fp32 or bf16 via fflag).
__global__ __launch_bounds__(256) void k_gemm_bn64(const ushort* __restrict__ A, int lda,
    const ushort* __restrict__ W, int ldb, int M, int Nc, int K,
    const void* __restrict__ bias, const void* __restrict__ g, const void* __restrict__ bb,
    const void* __restrict__ rm, const void* __restrict__ rv, const int* __restrict__ fflag,
    const int* __restrict__ rp, ushort* __restrict__ H){
  const int MT = (M + 63) >> 6;
  const int YC = Nc >> 7;            // 2 (Od=256) / 1 (Od=128)
  int jb = blockIdx.x;
  int gx = jb & 7, rr = jb >> 3;
  int sx = rr / YC, yy = rr % YC;
  const int Tm = sx*8 + gx;
  if (Tm >= MT) return;
  __shared__ ushort As[64*32];
  __shared__ ushort Bs[128*32];
  const int t = threadIdx.x;
  const int lane = t & 63;
  const int wv = t >> 6;
  const int m0 = Tm*64;
  const int n0 = yy*128;
  const int lr = lane & 15;
  const int qq = lane >> 4;
  int srowA = t >> 2, sqA = t & 3;
  int ga = m0 + srowA; if (ga >= M) ga = M - 1;
  int srowB0 = t >> 2,        srowB1 = 64 + (t >> 2);
  f32x4 acc[8];
  #pragma unroll
  for (int j = 0; j < 8; j++) acc[j] = {0.f,0.f,0.f,0.f};
  for (int k0 = 0; k0 < K; k0 += 32){
    ld16(A + (size_t)ga*lda + k0 + sqA*8, &As[(size_t)t*8]);
    ld16(W + (size_t)(n0 + srowB0)*ldb + k0 + sqA*8, &Bs[(size_t)t*8]);
    ld16(W + (size_t)(n0 + srowB1)*ldb + k0 + sqA*8, &Bs[(size_t)(256+t)*8]);
    __syncthreads();
    bf16x8 a = *(const bf16x8*)&As[(wv*16 + lr)*32 + qq*8];
    #pragma unroll
    for (int j = 0; j < 8; j++){
      bf16x8 b = *(const bf16x8*)&Bs[(j*16 + lr)*32 + qq*8];
      acc[j] = __builtin_amdgcn_mfma_f32_16x16x32_bf16(a, b, acc[j], 0, 0, 0);
    }
    __syncthreads();
  }
  int f = *fflag;
  float bi[8], sc[8], sh[8];
  #pragma unroll
  for (int j = 0; j < 8; j++){
    int col = n0 + j*16 + lr;
    bi[j] = ldf(bias, f, col);
    sc[j] = ldf(g, f, col) * rsqrtf(ldf(rv, f, col) + 1e-5f);
    sh[j] = ldf(bb, f, col) - ldf(rm, f, col) * sc[j];
  }
  #pragma unroll
  for (int r = 0; r < 4; r++){
    int row = m0 + wv*16 + qq*4 + r;
    if (row >= M) continue;
    int empty = (rp[row+1] - rp[row] == 0);
    #pragma unroll
    for (int j = 0; j < 8; j++){
      float v = acc[j][r] + bi[j];
      if (empty) v = 0.f;
      H[(size_t)row*Nc + n0 + j*16 + lr] = f2b(fmaxf(v*sc[j] + sh[j], 0.f));
    }
  }
}

// ---------- per-node edge aggregation (fp8 Q + bf16 eh + srcs) ----------
// 2 nodes/block, NO barriers/LDS; thread t owns channels {2t,2t+1};
// 2-edge ILP unroll.  QF8: Q rows are fp8 e4m3, decoded by HW
// v_cvt_pk_f32_fp8 (1 inst per 2 channels).  eh read as packed bf16 in
// CSR order (sequential).  MU may alias P (read-before-write per thread).
template<int C, int QF8>
__global__ __launch_bounds__(256) void k_msg4(const ushort* P, const void* __restrict__ Qv,
    const uint* __restrict__ ehb, const ushort* __restrict__ w1, const void* __restrict__ b1,
    const int* __restrict__ fflag, const int* __restrict__ rp, const int* __restrict__ srcs,
    ushort* MU, int N){
  int t = threadIdx.x;
  int c0 = t*2;
  f32x2 wc[16];
  {
    float a0[16], a1[16];
    const uint4* wp0 = (const uint4*)(w1 + (size_t)c0*528 + 512);
    const uint4* wp1 = (const uint4*)(w1 + (size_t)(c0+1)*528 + 512);
    unpack8(wp0[0], a0); unpack8(wp0[1], a0+8);
    unpack8(wp1[0], a1); unpack8(wp1[1], a1+8);
    #pragma unroll
    for (int j = 0; j < 16; j++){ wc[j].x = a0[j]; wc[j].y = a1[j]; }
  }
  int ff = *fflag;
  f32x2 b1v = { ldf(b1, ff, c0), ldf(b1, ff, c0+1) };
  int nb = blockIdx.x*2;
  int ne = nb + 2; if (ne > N) ne = N;
  for (int n = nb; n < ne; n++){
    const int i0 = rp[n], i1 = rp[n+1];
    uint pw = *(const uint*)(P + (size_t)n*C + c0);
    f32x2 pre = { lo2f(pw) + b1v.x, hi2f(pw) + b1v.y };
    f32x2 acc0 = {0.f, 0.f}, acc1 = {0.f, 0.f};
    int i = i0;
    for (; i + 2 <= i1; i += 2){
      int s0 = srcs[i], s1 = srcs[i+1];
      f32x2 q0, q1;
      if constexpr (QF8){
        ushort qa = *(const ushort*)((const uchar*)Qv + (size_t)s0*C + c0);
        ushort qb = *(const ushort*)((const uchar*)Qv + (size_t)s1*C + c0);
        q0 = __builtin_amdgcn_cvt_pk_f32_fp8((uint)qa, false);
        q1 = __builtin_amdgcn_cvt_pk_f32_fp8((uint)qb, false);
      } else {
        uint qa = *(const uint*)((const ushort*)Qv + (size_t)s0*C + c0);
        uint qb = *(const uint*)((const ushort*)Qv + (size_t)s1*C + c0);
        q0 = (f32x2){ lo2f(qa), hi2f(qa) };
        q1 = (f32x2){ lo2f(qb), hi2f(qb) };
      }
      const uint4* ep = (const uint4*)(ehb + (size_t)i*8);
      uint4 ea = ep[0], eb = ep[1], ec = ep[2], ed = ep[3];
      float ef0[16], ef1[16];
      unpack8(ea, ef0); unpack8(eb, ef0+8);
      unpack8(ec, ef1); unpack8(ed, ef1+8);
      f32x2 d0 = { pre.x + q0.x, pre.y + q0.y };
      f32x2 d1 = { pre.x + q1.x, pre.y + q1.y };
      #pragma unroll
      for (int j = 0; j < 16; j++){
        f32x2 e0v = {ef0[j], ef0[j]};
        f32x2 e1v = {ef1[j], ef1[j]};
        d0 += wc[j] * e0v;
        d1 += wc[j] * e1v;
      }
      acc0.x += fmaxf(d0.x, 0.f); acc0.y += fmaxf(d0.y, 0.f);
      acc1.x += fmaxf(d1.x, 0.f); acc1.y += fmaxf(d1.y, 0.f);
    }
    if (i < i1){
      int s0 = srcs[i];
      f32x2 q0;
      if constexpr (QF8){
        ushort qa = *(const ushort*)((const uchar*)Qv + (size_t)s0*C + c0);
        q0 = __builtin_amdgcn_cvt_pk_f32_fp8((uint)qa, false);
      } else {
        uint qa = *(const uint*)((const ushort*)Qv + (size_t)s0*C + c0);
        q0 = (f32x2){ lo2f(qa), hi2f(qa) };
      }
      const uint4* ep = (const uint4*)(ehb + (size_t)i*8);
      uint4 ea = ep[0], eb = ep[1];
      float ef0[16];
      unpack8(ea, ef0); unpack8(eb, ef0+8);
      f32x2 d0 = { pre.x + q0.x, pre.y + q0.y };
      #pragma unroll
      for (int j = 0; j < 16; j++){
        f32x2 e0v = {ef0[j], ef0[j]};
        d0 += wc[j] * e0v;
      }
      acc0.x += fmaxf(d0.x, 0.f); acc0.y += fmaxf(d0.y, 0.f);
    }
    int cnt = i1 - i0;
    float inv = (cnt > 0) ? 1.f/(float)cnt : 0.f;
    *(uint*)(MU + (size_t)n*C + c0) = pk2((acc0.x + acc1.x)*inv, (acc0.y + acc1.y)*inv);
  }
}

// ---------- pooling + FC + sigmoid (all params raw) ----------
__global__ __launch_bounds__(128) void k_pool(const ushort* __restrict__ h, const void* __restrict__ batch,
    const int* __restrict__ iflag, const void* __restrict__ fw, const void* __restrict__ fb,
    const int* __restrict__ fflag, void* __restrict__ out, int N){
  int g = blockIdx.x, t = threadIdx.x;
  int ifl = *iflag;
  int lo = 0, hi = N;
  while (lo < hi){ int mid = (lo+hi) >> 1; if (ld_idx(batch, ifl, mid) <  g) lo = mid+1; else hi = mid; }
  int s0 = lo;
  hi = N;
  while (lo < hi){ int mid = (lo+hi) >> 1; if (ld_idx(batch, ifl, mid) <= g) lo = mid+1; else hi = mid; }
  int s1 = lo;
  float s = 0.f;
  for (int i = s0; i < s1; i++) s += b2f(h[(size_t)i*128 + t]);
  int cnt = s1 - s0;
  __shared__ float ps[128];
  ps[t] = s / (float)(cnt > 0 ? cnt : 1);
  __syncthreads();
  int f = *fflag;
  if (t < 12){
    float z = ldf(fb, f, t);
    for (int j = 0; j < 128; j++) z += ps[j]*ldf(fw, f, t*128 + j);
    float r = 1.f/(1.f + expf(-z));
    if (f) ((float*)out)[g*12 + t] = r;
    else   ((ushort*)out)[g*12 + t] = f2b(r);
  }
}

__global__ __launch_bounds__(256) void k_sentinel(ushort* __restrict__ out, int n){
  int i = blockIdx.x*256 + threadIdx.x;
  if (i < n) out[i] = 0x3F00;
}

extern "C" void kernel_launch(void* const* d_in, const int* in_sizes, int n_in,
                              void* d_out, int out_size, void* d_ws, size_t ws_size,
                              hipStream_t stream){
  const void* x_raw   = d_in[0];
  const void* ei_raw  = d_in[1];
  const void* ea_raw  = d_in[2];
  const void* ba_raw  = d_in[3];
  (void)n_in;

  const int N = in_sizes[3];        // 20000
  const int E = in_sizes[1] / 2;    // 200000
  const int G = out_size / 12;      // 512

  // ---- workspace plan ----
  char* base = (char*)d_ws;
  size_t off = 0;
  auto alloc = [&](size_t bytes)->char*{
    char* p = base + off;
    off = (off + bytes + 255) & ~(size_t)255;
    return p;
  };
  int* iflag    = (int*)alloc(256);
  int* fflag    = (int*)alloc(256);
  int* deg      = (int*)alloc((size_t)N*4);
  int* fill     = (int*)alloc((size_t)N*4);   // contiguous-ish after deg
  int zn        = (int)(fill - deg) + N;      // ints to zero covering both
  int* rp       = (int*)alloc((size_t)(N+1)*4);
  int2* cpair   = (int2*)alloc((size_t)E*8);
  int* srcs     = (int*)alloc((size_t)E*4);
  ushort* w1c[3], *w2c[3];
  const int w1n[3] = {512*528, 512*528, 256*528};
  const int w2n[3] = {256*512, 256*512, 128*256};
  for (int i = 0; i < 3; i++) w1c[i] = (ushort*)alloc((size_t)w1n[i]*2);
  for (int i = 0; i < 3; i++) w2c[i] = (ushort*)alloc((size_t)w2n[i]*2);
  float*  e_h32 = (float*)alloc((size_t)E*16*4);    // 12.8 MB, edge-id order, f32
  uint*   ehb   = (uint*)alloc((size_t)E*32);       // 6.4 MB, CSR order, bf16x2
  ushort* h     = (ushort*)alloc((size_t)N*256*2);
  ushort* Q     = (ushort*)alloc((size_t)N*512*2);  // bf16 Q (layer 2)
  uchar*  Qf8   = (uchar*)alloc((size_t)N*512);     // fp8 Q (layers 0/1)
  ushort* PM    = (ushort*)alloc((size_t)N*512*2);

  if (off > ws_size){
    k_sentinel<<<(out_size + 255)/256, 256, 0, stream>>>((ushort*)d_out, out_size);
    return;
  }

  // ---- zero+probe, count, scan ----
  k_zero_probe<<<(zn + 255)/256, 256, 0, stream>>>((const uint*)ei_raw, (const uint*)x_raw,
                                                   iflag, fflag, deg, zn);
  k_count<<<(E + 255)/256, 256, 0, stream>>>(ei_raw, iflag, deg, E, N);
  k_scan<<<1, 1024, 0, stream>>>(deg, rp, N);

  // ---- mega: fill + weight cvt + encoders ----
  CvtTab ct; ct.nseg = 6;
  const void* csrcs[6] = {d_in[8], d_in[16], d_in[24], d_in[10], d_in[18], d_in[26]};
  ushort* cdsts[6]     = {w1c[0],  w1c[1],   w1c[2],   w2c[0],   w2c[1],   w2c[2]};
  const int cns[6]     = {w1n[0],  w1n[1],   w1n[2],   w2n[0],   w2n[1],   w2n[2]};
  int bacc = 0;
  for (int i = 0; i < 6; i++){
    ct.src[i] = csrcs[i]; ct.dst[i] = cdsts[i]; ct.n[i] = cns[i];
    ct.bstart[i] = bacc; bacc += (cns[i] + 8191)/8192;
  }
  int FB = (E + 255)/256;
  int CB = bacc;
  int EB = (E + 255)/256;
  int NB = (N + 3)/4;
  k_mega<<<FB + CB + EB + NB, 256, 0, stream>>>(
      ei_raw, iflag, rp, fill, cpair, ct, fflag,
      ea_raw, d_in[4], d_in[5], x_raw, d_in[6], d_in[7],
      e_h32, h, E, N, FB, CB, EB);

  // ---- eh -> CSR-order bf16 + srcs ----
  k_reorder<<<(E + 255)/256, 256, 0, stream>>>(cpair, e_h32, ehb, srcs, E);

  // ---- 3 conv layers ----
  const int Cch[3] = {512, 512, 256};
  const int Od[3]  = {256, 256, 128};
  const int MTpq = (N + 127)/128;
  const int MTbn = (N + 63)/64;
  for (int i = 0; i < 3; i++){
    int di = 8 + 8*i;
    int g1 = 8 * ((MTpq + 7)/8) * (Cch[i] >> 6);
    dim3 gm((N + 1)/2);
    if (i < 2){
      k_gemm_pq_lds<1><<<g1, 256, 0, stream>>>(h, w1c[i], N, Cch[i], PM, Qf8);
      k_msg4<512,1><<<gm, 256, 0, stream>>>(PM, Qf8, ehb, w1c[i], d_in[di+1], fflag, rp, srcs, PM, N);
    } else {
      k_gemm_pq_lds<0><<<g1, 256, 0, stream>>>(h, w1c[i], N, Cch[i], PM, Q);
      k_msg4<256,0><<<gm, 128, 0, stream>>>(PM, Q, ehb, w1c[i], d_in[di+1], fflag, rp, srcs, PM, N);
    }
    int g2 = 8 * ((MTbn + 7)/8) * (Od[i] >> 7);
    k_gemm_bn64<<<g2, 256, 0, stream>>>(PM, Cch[i], w2c[i], Cch[i], N, Od[i], Cch[i],
                                        d_in[di+3], d_in[di+4], d_in[di+5],
                                        d_in[di+6], d_in[di+7], fflag, rp, h);
  }

  // ---- mean pool + FC + sigmoid ----
  k_pool<<<G, 128, 0, stream>>>(h, ba_raw, iflag, d_in[32], d_in[33], fflag, d_out, N);
}

// Round 6
// 484.494 us; speedup vs baseline: 1.0554x; 1.0554x over previous
//
// GCNTox21 fused pipeline — MI355X/gfx950.  R18: consolidation.
// Ledger: R13 LDS-stage regressed (72->81), R14 prefetch neutral-alone,
// R15 seq-eh+XCD-remap 486us (best), R17 fp8-Q halved FETCH (110->57MB)
// but msg4 got SLOWER (68->76.6) => msg4 is structure-bound (~41us VALU
// issue + imperfectly overlapped gather), invariant to bytes/concurrency.
// R18 = exact R15 msg4 (prefetch, f32 ehp, bf16 Q) + exact R15 GEMMs,
// fp8 dropped, and the edge-encoder MLP folded into the reorder kernel
// (k_edge: gather ea[cpair.y], MLP, write ehp sequential) — removes the
// eh intermediate (~19MB traffic) and 782 mega blocks.  Numerics of the
// MLP are order-identical to the old mega-enc path.
#include <hip/hip_runtime.h>
#include <hip/hip_bf16.h>

typedef unsigned int  uint;
typedef unsigned short ushort;
typedef float  f32x2  __attribute__((ext_vector_type(2)));
typedef float  f32x4  __attribute__((ext_vector_type(4)));
typedef __bf16 bf16x8 __attribute__((ext_vector_type(8)));

#define DEV static __device__ __forceinline__

DEV float  b2f(ushort b){ return __uint_as_float(((uint)b) << 16); }
DEV float  lo2f(uint u){ return __uint_as_float(u << 16); }
DEV float  hi2f(uint u){ return __uint_as_float(u & 0xffff0000u); }
DEV ushort f2b(float f){           // RNE float->bf16
  uint u = __float_as_uint(f);
  u += 0x7fffu + ((u >> 16) & 1u);
  return (ushort)(u >> 16);
}
DEV uint pk2(float a, float b){ return (uint)f2b(a) | ((uint)f2b(b) << 16); }
DEV void unpack8(uint4 v, float* f){
  f[0]=lo2f(v.x); f[1]=hi2f(v.x); f[2]=lo2f(v.y); f[3]=hi2f(v.y);
  f[4]=lo2f(v.z); f[5]=hi2f(v.z); f[6]=lo2f(v.w); f[7]=hi2f(v.w);
}
DEV int ld_idx(const void* p, int flag, long long i){
  return flag ? ((const int*)p)[i] : (int)((const long long*)p)[i];
}
DEV float ldf(const void* p, int f, int i){
  return f ? ((const float*)p)[i] : b2f(((const ushort*)p)[i]);
}
DEV int clampi(int v, int lo, int hi){ return v < lo ? lo : (v > hi ? hi : v); }

// async 16B global -> LDS (DMA).  LDS dest = wave-uniform base + lane*16.
DEV void ld16(const ushort* g, ushort* l){
  __builtin_amdgcn_global_load_lds(
      (const __attribute__((address_space(1))) void*)g,
      (__attribute__((address_space(3))) void*)l, 16, 0, 0);
}

// ---------- zero (deg+fill) + probes in one launch ----------
__global__ __launch_bounds__(256) void k_zero_probe(const uint* __restrict__ ei,
    const uint* __restrict__ xw, int* __restrict__ iflag, int* __restrict__ fflag,
    int* __restrict__ zbase, int zn){
  int i = blockIdx.x*256 + threadIdx.x;
  if (i < zn) zbase[i] = 0;
  if (blockIdx.x == 0){
    __shared__ int anyI, cntF;
    if (threadIdx.x == 0){ anyI = 0; cntF = 0; }
    __syncthreads();
    int li = 0, lc = 0;
    for (int k = threadIdx.x; k < 1024; k += 256){
      if (ei[2*k + 1] != 0u) li = 1;            // int64 => odd words all 0
      float f = fabsf(__uint_as_float(xw[k]));  // fp32 N(0,1) words decode sane
      if (f > 1e-6f && f < 1e6f) lc++;
    }
    if (li) atomicOr(&anyI, 1);
    atomicAdd(&cntF, lc);
    __syncthreads();
    if (threadIdx.x == 0){ *iflag = anyI; *fflag = (2*cntF > 1024) ? 1 : 0; }
  }
}

// ---------- CSR count + scan ----------
__global__ __launch_bounds__(256) void k_count(const void* __restrict__ ei,
    const int* __restrict__ flag, int* __restrict__ cnt, int E, int N){
  int e = blockIdx.x*256 + threadIdx.x;
  if (e >= E) return;
  int d = clampi(ld_idx(ei, *flag, (long long)E + e), 0, N-1);
  atomicAdd(&cnt[d], 1);
}

__global__ __launch_bounds__(1024) void k_scan(const int* __restrict__ deg, int* __restrict__ rp, int n){
  __shared__ int part[1024];
  int t = threadIdx.x;
  int chunk = (n + 1023) >> 10;
  int base = t * chunk;
  int s = 0;
  for (int i = 0; i < chunk; i++){ int j = base + i; if (j < n) s += deg[j]; }
  part[t] = s;
  __syncthreads();
  for (int off = 1; off < 1024; off <<= 1){
    int v = (t >= off) ? part[t - off] : 0;
    __syncthreads();
    part[t] += v;
    __syncthreads();
  }
  int run = part[t] - s;
  for (int i = 0; i < chunk; i++){ int j = base + i; if (j < n){ rp[j] = run; run += deg[j]; } }
  if (t == 1023) rp[n] = part[1023];
}

// ---------- mega: CSR-fill + weight-cvt + node-enc (edge-enc moved out) ----
struct CvtTab { const void* src[6]; ushort* dst[6]; int n[6]; int bstart[6]; int nseg; };

__global__ __launch_bounds__(256) void k_mega(
    const void* __restrict__ ei, const int* __restrict__ iflag,
    const int* __restrict__ rp, int* __restrict__ fill, int2* __restrict__ cpair,
    CvtTab ct, const int* __restrict__ fflag,
    const void* __restrict__ x, const void* __restrict__ nw, const void* __restrict__ nbias,
    ushort* __restrict__ h,
    int E, int N, int FB, int CB){
  int b = blockIdx.x;
  int t = threadIdx.x;
  if (b < FB){
    // ---- CSR fill ----
    int e = b*256 + t;
    if (e >= E) return;
    int f = *iflag;
    int s = clampi(ld_idx(ei, f, e), 0, N-1);
    int d = clampi(ld_idx(ei, f, (long long)E + e), 0, N-1);
    int pos = clampi(rp[d] + atomicAdd(&fill[d], 1), 0, E-1);
    cpair[pos] = make_int2(s, e);
  } else if (b < FB + CB){
    // ---- weight conversion (w1 x3, w2 x3) ----
    int cb = b - FB;
    int s = ct.nseg - 1;
    for (int i = 1; i < ct.nseg; i++) if (cb < ct.bstart[i]){ s = i - 1; break; }
    int rel = cb - ct.bstart[s];
    const void* sp = ct.src[s];
    ushort* d = ct.dst[s];
    int f = *fflag;
    int end = ct.n[s]; int cap = rel*8192 + 8192; if (cap < end) end = cap;
    for (int i = rel*8192 + t; i < end; i += 256)
      d[i] = f ? f2b(((const float*)sp)[i]) : ((const ushort*)sp)[i];
  } else {
    // ---- node encoder: h = relu(x @ nw.T + nb), 4 nodes/block ----
    __shared__ float xs[4][32];
    int f = *fflag;
    int nb = (b - FB - CB)*4;
    if (t < 128){
      int ni = t >> 5, ci = t & 31;
      int n = nb + ni; if (n >= N) n = N - 1;
      xs[ni][ci] = f ? ((const float*)x)[(size_t)n*32 + ci]
                     : b2f(((const ushort*)x)[(size_t)n*32 + ci]);
    }
    __syncthreads();
    float wr[32];
    if (f){
      const float4* wp = (const float4*)((const float*)nw + (size_t)t*32);
      #pragma unroll
      for (int q4 = 0; q4 < 8; q4++){
        float4 v = wp[q4];
        wr[q4*4+0]=v.x; wr[q4*4+1]=v.y; wr[q4*4+2]=v.z; wr[q4*4+3]=v.w;
      }
    } else {
      const uint4* wp = (const uint4*)((const ushort*)nw + (size_t)t*32);
      unpack8(wp[0], wr); unpack8(wp[1], wr+8); unpack8(wp[2], wr+16); unpack8(wp[3], wr+24);
    }
    float bv = ldf(nbias, f, t);
    #pragma unroll
    for (int ni = 0; ni < 4; ni++){
      int n = nb + ni;
      if (n >= N) break;
      float s = bv;
      #pragma unroll
      for (int k = 0; k < 32; k++) s += xs[ni][k]*wr[k];
      h[(size_t)n*256 + t] = f2b(fmaxf(s, 0.f));
    }
  }
}

// ---------- fused edge-encoder + reorder: ehp[pos] = relu(ea[cpair[pos].y] @ eew.T + eeb) ----
// Gathers the small raw ea rows (32B fp32 / 16B bf16), computes the 8->16
// MLP (order-identical to the old mega-enc), writes ehp sequentially in
// CSR-position order.
__global__ __launch_bounds__(256) void k_edge(const int2* __restrict__ cpair,
    const void* __restrict__ ea, const void* __restrict__ eew, const void* __restrict__ eeb,
    const int* __restrict__ fflag, float* __restrict__ ehp, int E){
  __shared__ float ws[128];
  __shared__ float bs[16];
  int f = *fflag;
  int t = threadIdx.x;
  if (t < 128) ws[t] = ldf(eew, f, t);
  if (t < 16)  bs[t] = ldf(eeb, f, t);
  __syncthreads();
  int pos = blockIdx.x*256 + t;
  if (pos >= E) return;
  int e = cpair[pos].y;
  float a[8];
  if (f){
    const float4* ap = (const float4*)((const float*)ea + (size_t)e*8);
    float4 v0 = ap[0], v1 = ap[1];
    a[0]=v0.x; a[1]=v0.y; a[2]=v0.z; a[3]=v0.w;
    a[4]=v1.x; a[5]=v1.y; a[6]=v1.z; a[7]=v1.w;
  } else {
    uint4 av = *(const uint4*)((const ushort*)ea + (size_t)e*8);
    unpack8(av, a);
  }
  float o[16];
  #pragma unroll
  for (int c = 0; c < 16; c++){
    float s = bs[c];
    #pragma unroll
    for (int j = 0; j < 8; j++) s += a[j]*ws[c*8+j];
    o[c] = fmaxf(s, 0.f);
  }
  f32x4* op = (f32x4*)(ehp + (size_t)pos*16);
  #pragma unroll
  for (int q4 = 0; q4 < 4; q4++){
    f32x4 v = {o[q4*4+0], o[q4*4+1], o[q4*4+2], o[q4*4+3]};
    op[q4] = v;
  }
}

// ---------- LDS-staged 128x128 GEMM: P/Q producer (XCD-affine remap) ----------
// Blocks sharing an A-tile (same m0) get linear ids === same (mod 8) so a
// round-robin XCD dispatch runs them on ONE XCD => A-tile L2-filled once.
__global__ __launch_bounds__(256) void k_gemm_pq_lds(const ushort* __restrict__ A,
    const ushort* __restrict__ w1, int M, int Nc,
    ushort* __restrict__ P, ushort* __restrict__ Q){
  const int MT = (M + 127) >> 7;
  const int YC = Nc >> 6;            // total y-variants: 8 (C=512) / 4 (C=256)
  int jb = blockIdx.x;
  int gx = jb & 7, rr = jb >> 3;
  int sx = rr / YC, yy = rr % YC;
  const int Tm = sx*8 + gx;
  if (Tm >= MT) return;
  __shared__ ushort As[128*32];
  __shared__ ushort Bs[128*32];
  const int t = threadIdx.x;
  const int lane = t & 63;
  const int wv = t >> 6;
  const int m0 = Tm*128;
  const int yc = Nc >> 7;
  const int isQ = yy >= yc;
  const int n0 = (isQ ? yy - yc : yy)*128;
  const ushort* W = w1 + (isQ ? 256 : 0);
  ushort* C = isQ ? Q : P;
  const int lr = lane & 15;
  const int qq = lane >> 4;
  int srow0 = t >> 2,         sq0 = t & 3;
  int srow1 = (256 + t) >> 2, sq1 = t & 3;
  int ga0 = m0 + srow0; if (ga0 >= M) ga0 = M - 1;
  int ga1 = m0 + srow1; if (ga1 >= M) ga1 = M - 1;
  f32x4 acc[2][8];
  #pragma unroll
  for (int f = 0; f < 2; f++)
    #pragma unroll
    for (int j = 0; j < 8; j++) acc[f][j] = {0.f,0.f,0.f,0.f};
  for (int k0 = 0; k0 < 256; k0 += 32){
    ld16(A + (size_t)ga0*256 + k0 + sq0*8, &As[(size_t)t*8]);
    ld16(A + (size_t)ga1*256 + k0 + sq1*8, &As[(size_t)(256+t)*8]);
    ld16(W + (size_t)(n0 + srow0)*528 + k0 + sq0*8, &Bs[(size_t)t*8]);
    ld16(W + (size_t)(n0 + srow1)*528 + k0 + sq1*8, &Bs[(size_t)(256+t)*8]);
    __syncthreads();
    bf16x8 a0 = *(const bf16x8*)&As[(wv*32 + lr)*32 + qq*8];
    bf16x8 a1 = *(const bf16x8*)&As[(wv*32 + 16 + lr)*32 + qq*8];
    #pragma unroll
    for (int j = 0; j < 8; j++){
      bf16x8 b = *(const bf16x8*)&Bs[(j*16 + lr)*32 + qq*8];
      acc[0][j] = __builtin_amdgcn_mfma_f32_16x16x32_bf16(a0, b, acc[0][j], 0, 0, 0);
      acc[1][j] = __builtin_amdgcn_mfma_f32_16x16x32_bf16(a1, b, acc[1][j], 0, 0, 0);
    }
    __syncthreads();
  }
  #pragma unroll
  for (int f = 0; f < 2; f++){
    #pragma unroll
    for (int r = 0; r < 4; r++){
      int row = m0 + wv*32 + f*16 + qq*4 + r;
      if (row >= M) continue;
      #pragma unroll
      for (int j = 0; j < 8; j++)
        C[(size_t)row*Nc + n0 + j*16 + lr] = f2b(acc[f][j][r]);
    }
  }
}

// ---------- LDS-staged 64x128 GEMM + bias + deg-mask + BN + relu ----------
// XCD-affine remap kept.  Small params read raw (fp32 or bf16 via fflag).
__global__ __launch_bounds__(256) void k_gemm_bn64(const ushort* __restrict__ A, int lda,
    const ushort* __restrict__ W, int ldb, int M, int Nc, int K,
    const void* __restrict__ bias, const void* __restrict__ g, const void* __restrict__ bb,
    const void* __restrict__ rm, const void* __restrict__ rv, const int* __restrict__ fflag,
    const int* __restrict__ rp, ushort* __restrict__ H){
  const int MT = (M + 63) >> 6;
  const int YC = Nc >> 7;            // 2 (Od=256) / 1 (Od=128)
  int jb = blockIdx.x;
  int gx = jb & 7, rr = jb >> 3;
  int sx = rr / YC, yy = rr % YC;
  const int Tm = sx*8 + gx;
  if (Tm >= MT) return;
  __shared__ ushort As[64*32];
  __shared__ ushort Bs[128*32];
  const int t = threadIdx.x;
  const int lane = t & 63;
  const int wv = t >> 6;
  const int m0 = Tm*64;
  const int n0 = yy*128;
  const int lr = lane & 15;
  const int qq = lane >> 4;
  int srowA = t >> 2, sqA = t & 3;
  int ga = m0 + srowA; if (ga >= M) ga = M - 1;
  int srowB0 = t >> 2,        srowB1 = 64 + (t >> 2);
  f32x4 acc[8];
  #pragma unroll
  for (int j = 0; j < 8; j++) acc[j] = {0.f,0.f,0.f,0.f};
  for (int k0 = 0; k0 < K; k0 += 32){
    ld16(A + (size_t)ga*lda + k0 + sqA*8, &As[(size_t)t*8]);
    ld16(W + (size_t)(n0 + srowB0)*ldb + k0 + sqA*8, &Bs[(size_t)t*8]);
    ld16(W + (size_t)(n0 + srowB1)*ldb + k0 + sqA*8, &Bs[(size_t)(256+t)*8]);
    __syncthreads();
    bf16x8 a = *(const bf16x8*)&As[(wv*16 + lr)*32 + qq*8];
    #pragma unroll
    for (int j = 0; j < 8; j++){
      bf16x8 b = *(const bf16x8*)&Bs[(j*16 + lr)*32 + qq*8];
      acc[j] = __builtin_amdgcn_mfma_f32_16x16x32_bf16(a, b, acc[j], 0, 0, 0);
    }
    __syncthreads();
  }
  int f = *fflag;
  float bi[8], sc[8], sh[8];
  #pragma unroll
  for (int j = 0; j < 8; j++){
    int col = n0 + j*16 + lr;
    bi[j] = ldf(bias, f, col);
    sc[j] = ldf(g, f, col) * rsqrtf(ldf(rv, f, col) + 1e-5f);
    sh[j] = ldf(bb, f, col) - ldf(rm, f, col) * sc[j];
  }
  #pragma unroll
  for (int r = 0; r < 4; r++){
    int row = m0 + wv*16 + qq*4 + r;
    if (row >= M) continue;
    int empty = (rp[row+1] - rp[row] == 0);
    #pragma unroll
    for (int j = 0; j < 8; j++){
      float v = acc[j][r] + bi[j];
      if (empty) v = 0.f;
      H[(size_t)row*Nc + n0 + j*16 + lr] = f2b(fmaxf(v*sc[j] + sh[j], 0.f));
    }
  }
}

// ---------- per-node edge aggregation (exact R15 form, proven 68us) ----------
// 2 nodes/block, NO barriers/LDS; thread t owns channels {2t,2t+1};
// 2-edge ILP unroll + 1-iteration Q/cpair prefetch.  eh read from ehp in
// CSR order => sequential 64B bursts.  MU may alias P.
template<int C>
__global__ __launch_bounds__(256) void k_msg4(const ushort* P, const ushort* __restrict__ Q,
    const float* __restrict__ ehp, const ushort* __restrict__ w1, const void* __restrict__ b1,
    const int* __restrict__ fflag, const int* __restrict__ rp, const int2* __restrict__ cpair,
    ushort* MU, int N){
  int t = threadIdx.x;
  int c0 = t*2;
  f32x2 wc[16];
  {
    float a0[16], a1[16];
    const uint4* wp0 = (const uint4*)(w1 + (size_t)c0*528 + 512);
    const uint4* wp1 = (const uint4*)(w1 + (size_t)(c0+1)*528 + 512);
    unpack8(wp0[0], a0); unpack8(wp0[1], a0+8);
    unpack8(wp1[0], a1); unpack8(wp1[1], a1+8);
    #pragma unroll
    for (int j = 0; j < 16; j++){ wc[j].x = a0[j]; wc[j].y = a1[j]; }
  }
  int ff = *fflag;
  f32x2 b1v = { ldf(b1, ff, c0), ldf(b1, ff, c0+1) };
  int nb = blockIdx.x*2;
  int ne = nb + 2; if (ne > N) ne = N;
  for (int n = nb; n < ne; n++){
    const int i0 = rp[n], i1 = rp[n+1];
    uint pw = *(const uint*)(P + (size_t)n*C + c0);
    f32x2 pre = { lo2f(pw) + b1v.x, hi2f(pw) + b1v.y };
    f32x2 acc0 = {0.f, 0.f}, acc1 = {0.f, 0.f};
    int i = i0;
    // ---- pipeline prologue: load edge pair i,i+1 (cpair then Q) ----
    int2 p0, p1; uint qw0, qw1;
    if (i + 2 <= i1){
      p0 = cpair[i]; p1 = cpair[i+1];
      qw0 = *(const uint*)(Q + (size_t)p0.x*C + c0);
      qw1 = *(const uint*)(Q + (size_t)p1.x*C + c0);
    }
    while (i + 2 <= i1){
      int inx = i + 2;
      bool more = (inx + 2 <= i1);          // block-uniform branch
      int2 np0, np1;
      if (more){ np0 = cpair[inx]; np1 = cpair[inx+1]; }   // issue early
      // eh loads for current pair: sequential CSR-order stream
      const f32x4* e0p = (const f32x4*)(ehp + (size_t)i*16);
      const f32x4* e1p = (const f32x4*)(ehp + (size_t)(i+1)*16);
      f32x4 ea0 = e0p[0], ea1 = e0p[1], ea2 = e0p[2], ea3 = e0p[3];
      f32x4 eb0 = e1p[0], eb1 = e1p[1], eb2 = e1p[2], eb3 = e1p[3];
      // issue next pair's Q gathers before the FMA chain
      uint nq0 = 0, nq1 = 0;
      if (more){
        nq0 = *(const uint*)(Q + (size_t)np0.x*C + c0);
        nq1 = *(const uint*)(Q + (size_t)np1.x*C + c0);
      }
      float ef0[16] = {ea0.x,ea0.y,ea0.z,ea0.w, ea1.x,ea1.y,ea1.z,ea1.w,
                       ea2.x,ea2.y,ea2.z,ea2.w, ea3.x,ea3.y,ea3.z,ea3.w};
      float ef1[16] = {eb0.x,eb0.y,eb0.z,eb0.w, eb1.x,eb1.y,eb1.z,eb1.w,
                       eb2.x,eb2.y,eb2.z,eb2.w, eb3.x,eb3.y,eb3.z,eb3.w};
      f32x2 d0 = { pre.x + lo2f(qw0), pre.y + hi2f(qw0) };
      f32x2 d1 = { pre.x + lo2f(qw1), pre.y + hi2f(qw1) };
      #pragma unroll
      for (int j = 0; j < 16; j++){
        f32x2 e0v = {ef0[j], ef0[j]};
        f32x2 e1v = {ef1[j], ef1[j]};
        d0 += wc[j] * e0v;
        d1 += wc[j] * e1v;
      }
      acc0.x += fmaxf(d0.x, 0.f); acc0.y += fmaxf(d0.y, 0.f);
      acc1.x += fmaxf(d1.x, 0.f); acc1.y += fmaxf(d1.y, 0.f);
      if (more){ p0 = np0; p1 = np1; qw0 = nq0; qw1 = nq1; }
      i = inx;
    }
    if (i < i1){
      // odd-degree tail: single edge, direct loads
      int2 t0 = cpair[i];
      uint tq0 = *(const uint*)(Q + (size_t)t0.x*C + c0);
      const f32x4* e0p = (const f32x4*)(ehp + (size_t)i*16);
      f32x4 ea0 = e0p[0], ea1 = e0p[1], ea2 = e0p[2], ea3 = e0p[3];
      float ef0[16] = {ea0.x,ea0.y,ea0.z,ea0.w, ea1.x,ea1.y,ea1.z,ea1.w,
                       ea2.x,ea2.y,ea2.z,ea2.w, ea3.x,ea3.y,ea3.z,ea3.w};
      f32x2 d0 = { pre.x + lo2f(tq0), pre.y + hi2f(tq0) };
      #pragma unroll
      for (int j = 0; j < 16; j++){
        f32x2 e0v = {ef0[j], ef0[j]};
        d0 += wc[j] * e0v;
      }
      acc0.x += fmaxf(d0.x, 0.f); acc0.y += fmaxf(d0.y, 0.f);
    }
    int cnt = i1 - i0;
    float inv = (cnt > 0) ? 1.f/(float)cnt : 0.f;
    *(uint*)(MU + (size_t)n*C + c0) = pk2((acc0.x + acc1.x)*inv, (acc0.y + acc1.y)*inv);
  }
}

// ---------- pooling + FC + sigmoid (all params raw) ----------
__global__ __launch_bounds__(128) void k_pool(const ushort* __restrict__ h, const void* __restrict__ batch,
    const int* __restrict__ iflag, const void* __restrict__ fw, const void* __restrict__ fb,
    const int* __restrict__ fflag, void* __restrict__ out, int N){
  int g = blockIdx.x, t = threadIdx.x;
  int ifl = *iflag;
  int lo = 0, hi = N;
  while (lo < hi){ int mid = (lo+hi) >> 1; if (ld_idx(batch, ifl, mid) <  g) lo = mid+1; else hi = mid; }
  int s0 = lo;
  hi = N;
  while (lo < hi){ int mid = (lo+hi) >> 1; if (ld_idx(batch, ifl, mid) <= g) lo = mid+1; else hi = mid; }
  int s1 = lo;
  float s = 0.f;
  for (int i = s0; i < s1; i++) s += b2f(h[(size_t)i*128 + t]);
  int cnt = s1 - s0;
  __shared__ float ps[128];
  ps[t] = s / (float)(cnt > 0 ? cnt : 1);
  __syncthreads();
  int f = *fflag;
  if (t < 12){
    float z = ldf(fb, f, t);
    for (int j = 0; j < 128; j++) z += ps[j]*ldf(fw, f, t*128 + j);
    float r = 1.f/(1.f + expf(-z));
    if (f) ((float*)out)[g*12 + t] = r;
    else   ((ushort*)out)[g*12 + t] = f2b(r);
  }
}

__global__ __launch_bounds__(256) void k_sentinel(ushort* __restrict__ out, int n){
  int i = blockIdx.x*256 + threadIdx.x;
  if (i < n) out[i] = 0x3F00;
}

extern "C" void kernel_launch(void* const* d_in, const int* in_sizes, int n_in,
                              void* d_out, int out_size, void* d_ws, size_t ws_size,
                              hipStream_t stream){
  const void* x_raw   = d_in[0];
  const void* ei_raw  = d_in[1];
  const void* ea_raw  = d_in[2];
  const void* ba_raw  = d_in[3];
  (void)n_in;

  const int N = in_sizes[3];        // 20000
  const int E = in_sizes[1] / 2;    // 200000
  const int G = out_size / 12;      // 512

  // ---- workspace plan ----
  char* base = (char*)d_ws;
  size_t off = 0;
  auto alloc = [&](size_t bytes)->char*{
    char* p = base + off;
    off = (off + bytes + 255) & ~(size_t)255;
    return p;
  };
  int* iflag    = (int*)alloc(256);
  int* fflag    = (int*)alloc(256);
  int* deg      = (int*)alloc((size_t)N*4);
  int* fill     = (int*)alloc((size_t)N*4);   // contiguous-ish after deg
  int zn        = (int)(fill - deg) + N;      // ints to zero covering both
  int* rp       = (int*)alloc((size_t)(N+1)*4);
  int2* cpair   = (int2*)alloc((size_t)E*8);
  ushort* w1c[3], *w2c[3];
  const int w1n[3] = {512*528, 512*528, 256*528};
  const int w2n[3] = {256*512, 256*512, 128*256};
  for (int i = 0; i < 3; i++) w1c[i] = (ushort*)alloc((size_t)w1n[i]*2);
  for (int i = 0; i < 3; i++) w2c[i] = (ushort*)alloc((size_t)w2n[i]*2);
  float*  ehp32 = (float*)alloc((size_t)E*16*4);    // 12.8 MB, CSR-pos order
  ushort* h     = (ushort*)alloc((size_t)N*256*2);
  ushort* Q     = (ushort*)alloc((size_t)N*512*2);
  ushort* PM    = (ushort*)alloc((size_t)N*512*2);

  if (off > ws_size){
    k_sentinel<<<(out_size + 255)/256, 256, 0, stream>>>((ushort*)d_out, out_size);
    return;
  }

  // ---- zero+probe, count, scan ----
  k_zero_probe<<<(zn + 255)/256, 256, 0, stream>>>((const uint*)ei_raw, (const uint*)x_raw,
                                                   iflag, fflag, deg, zn);
  k_count<<<(E + 255)/256, 256, 0, stream>>>(ei_raw, iflag, deg, E, N);
  k_scan<<<1, 1024, 0, stream>>>(deg, rp, N);

  // ---- mega: fill + weight cvt + node-enc ----
  CvtTab ct; ct.nseg = 6;
  const void* csrcs[6] = {d_in[8], d_in[16], d_in[24], d_in[10], d_in[18], d_in[26]};
  ushort* cdsts[6]     = {w1c[0],  w1c[1],   w1c[2],   w2c[0],   w2c[1],   w2c[2]};
  const int cns[6]     = {w1n[0],  w1n[1],   w1n[2],   w2n[0],   w2n[1],   w2n[2]};
  int bacc = 0;
  for (int i = 0; i < 6; i++){
    ct.src[i] = csrcs[i]; ct.dst[i] = cdsts[i]; ct.n[i] = cns[i];
    ct.bstart[i] = bacc; bacc += (cns[i] + 8191)/8192;
  }
  int FB = (E + 255)/256;
  int CB = bacc;
  int NB = (N + 3)/4;
  k_mega<<<FB + CB + NB, 256, 0, stream>>>(
      ei_raw, iflag, rp, fill, cpair, ct, fflag,
      x_raw, d_in[6], d_in[7], h, E, N, FB, CB);

  // ---- fused edge-encode + reorder -> ehp (CSR order) ----
  k_edge<<<(E + 255)/256, 256, 0, stream>>>(cpair, ea_raw, d_in[4], d_in[5],
                                            fflag, ehp32, E);

  // ---- 3 conv layers ----
  const int Cch[3] = {512, 512, 256};
  const int Od[3]  = {256, 256, 128};
  const int MTpq = (N + 127)/128;
  const int MTbn = (N + 63)/64;
  for (int i = 0; i < 3; i++){
    int di = 8 + 8*i;
    int g1 = 8 * ((MTpq + 7)/8) * (Cch[i] >> 6);
    k_gemm_pq_lds<<<g1, 256, 0, stream>>>(h, w1c[i], N, Cch[i], PM, Q);
    dim3 gm((N + 1)/2);
    if (i < 2) k_msg4<512><<<gm, 256, 0, stream>>>(PM, Q, ehp32, w1c[i], d_in[di+1], fflag, rp, cpair, PM, N);
    else       k_msg4<256><<<gm, 128, 0, stream>>>(PM, Q, ehp32, w1c[i], d_in[di+1], fflag, rp, cpair, PM, N);
    int g2 = 8 * ((MTbn + 7)/8) * (Od[i] >> 7);
    k_gemm_bn64<<<g2, 256, 0, stream>>>(PM, Cch[i], w2c[i], Cch[i], N, Od[i], Cch[i],
                                        d_in[di+3], d_in[di+4], d_in[di+5],
                                        d_in[di+6], d_in[di+7], fflag, rp, h);
  }

  // ---- mean pool + FC + sigmoid ----
  k_pool<<<G, 128, 0, stream>>>(h, ba_raw, iflag, d_in[32], d_in[33], fflag, d_out, N);
}